// Round 1
// baseline (161.745 us; speedup 1.0000x reference)
//
#include <hip/hip_runtime.h>
#include <stdint.h>

#define HD 512
#define NH 8
#define DH 64
#define SEQ 2048
#define BATCH 2
#define M_TOTAL (BATCH*SEQ)   // 4096
#define N_QKV (3*HD)          // 1536
#define K_DIM HD              // 512

typedef short bf16x8 __attribute__((ext_vector_type(8)));
typedef float f32x4 __attribute__((ext_vector_type(4)));

__device__ __forceinline__ uint16_t f2bf(float f) {
  union { float f; uint32_t u; } v; v.f = f;
  uint32_t u = v.u;
  return (uint16_t)((u + 0x7FFFu + ((u >> 16) & 1u)) >> 16);
}

__device__ __forceinline__ void gload_lds16(const void* g, void* l) {
  __builtin_amdgcn_global_load_lds(
      (const __attribute__((address_space(1))) void*)g,
      (__attribute__((address_space(3))) void*)l,
      16, 0, 0);
}

__global__ void convert_f32_to_bf16(const float* __restrict__ in,
                                    uint16_t* __restrict__ out, int n4) {
  int i = blockIdx.x * blockDim.x + threadIdx.x;
  if (i < n4) {
    float4 v = reinterpret_cast<const float4*>(in)[i];
    ushort4 o;
    o.x = f2bf(v.x); o.y = f2bf(v.y); o.z = f2bf(v.z); o.w = f2bf(v.w);
    reinterpret_cast<ushort4*>(out)[i] = o;
  }
}

// ---------------- QKV GEMM: C[4096,1536] = X[4096,512] @ W^T (W is [1536,512]) ----
#define BM 128
#define BN 128
#define BK 64

__global__ __launch_bounds__(256)
void qkv_gemm(const uint16_t* __restrict__ A,   // x bf16 [4096][512]
              const uint16_t* __restrict__ Bw,  // W bf16 [1536][512]
              uint16_t* __restrict__ C) {       // qkv bf16 [4096][1536]
  __shared__ __align__(16) uint16_t As[BM * BK];  // [row][slot^ (row&7)] 16B slots
  __shared__ __align__(16) uint16_t Bs[BN * BK];

  const int t = threadIdx.x;
  const int lane = t & 63;
  const int w = t >> 6;
  const int wr = w >> 1, wc = w & 1;
  const int l15 = lane & 15, l4 = lane >> 4;
  const int m0 = blockIdx.y * BM;
  const int n0 = blockIdx.x * BN;

  f32x4 acc[4][4] = {};

  for (int k0 = 0; k0 < K_DIM; k0 += BK) {
    __syncthreads();
#pragma unroll
    for (int i = 0; i < 4; ++i) {
      int idx = t + 256 * i;              // 0..1023 : row(128) x slot(8)
      int row = idx >> 3, slot = idx & 7;
      int src = slot ^ (row & 7);         // inverse-swizzle the SOURCE (rule 21)
      gload_lds16(A + (size_t)(m0 + row) * K_DIM + k0 + src * 8,
                  (char*)As + idx * 16);
      gload_lds16(Bw + (size_t)(n0 + row) * K_DIM + k0 + src * 8,
                  (char*)Bs + idx * 16);
    }
    __syncthreads();  // drains vmcnt for global_load_lds

#pragma unroll
    for (int kk = 0; kk < 2; ++kk) {      // two K=32 sub-steps
      bf16x8 af[4], bfr[4];
#pragma unroll
      for (int i = 0; i < 4; ++i) {
        int rowa = wr * 64 + i * 16 + l15;
        int sa = (kk * 4 + l4) ^ (rowa & 7);
        af[i] = *reinterpret_cast<const bf16x8*>((const char*)As + rowa * 128 + sa * 16);
        int rowb = wc * 64 + i * 16 + l15;
        int sb = (kk * 4 + l4) ^ (rowb & 7);
        bfr[i] = *reinterpret_cast<const bf16x8*>((const char*)Bs + rowb * 128 + sb * 16);
      }
#pragma unroll
      for (int i = 0; i < 4; ++i)
#pragma unroll
        for (int j = 0; j < 4; ++j)
          acc[i][j] = __builtin_amdgcn_mfma_f32_16x16x32_bf16(af[i], bfr[j], acc[i][j], 0, 0, 0);
    }
  }

  // epilogue: store bf16; fold temperature (0.125) into q columns
#pragma unroll
  for (int i = 0; i < 4; ++i) {
    int row = m0 + wr * 64 + i * 16 + l4 * 4;
#pragma unroll
    for (int j = 0; j < 4; ++j) {
      int col = n0 + wc * 64 + j * 16 + l15;
      float sc = ((col % 192) < 64) ? 0.125f : 1.0f;
#pragma unroll
      for (int jj = 0; jj < 4; ++jj)
        C[(size_t)(row + jj) * N_QKV + col] = f2bf(acc[i][j][jj] * sc);
    }
  }
}

// ---------------- Flash attention: per (b,h), Q-block 64 rows, KV tiles of 64 ----
__global__ __launch_bounds__(256)
void attn(const uint16_t* __restrict__ qkv, float* __restrict__ out) {
  __shared__ __align__(16) uint16_t Kt[64 * 64];      // [key][d]  swizzled slots
  __shared__ __align__(16) uint16_t Vt[64 * 64];      // [d][key]  swizzled slots
  __shared__ __align__(16) uint16_t Pl[4][16 * 64];   // per-wave [q][key] swizzled

  const int t = threadIdx.x;
  const int lane = t & 63;
  const int w = t >> 6;
  const int l15 = lane & 15, l4 = lane >> 4;
  const int bh = blockIdx.y;
  const int b = bh >> 3, h = bh & 7;
  const int q0 = blockIdx.x * 64;
  const int qw = q0 + w * 16;

  // Q fragments (q pre-scaled by temperature in GEMM epilogue)
  bf16x8 qf[2];
  {
    const uint16_t* qp = qkv + (size_t)(b * SEQ + qw + l15) * N_QKV + h * 192;
#pragma unroll
    for (int kk = 0; kk < 2; ++kk)
      qf[kk] = *reinterpret_cast<const bf16x8*>(qp + kk * 32 + l4 * 8);
  }

  f32x4 o[4] = {};
  float mrow[4], lrow[4];
#pragma unroll
  for (int jj = 0; jj < 4; ++jj) { mrow[jj] = -1e30f; lrow[jj] = 0.0f; }

  for (int s0 = 0; s0 < SEQ; s0 += 64) {
    __syncthreads();  // previous tile consumed
    // stage K [64 keys][64 d] via global_load_lds (source pre-swizzled)
#pragma unroll
    for (int i = 0; i < 2; ++i) {
      int idx = t + 256 * i;
      int row = idx >> 3, slot = idx & 7;
      int src = slot ^ (row & 7);
      gload_lds16(qkv + (size_t)(b * SEQ + s0 + row) * N_QKV + h * 192 + 64 + src * 8,
                  (char*)Kt + idx * 16);
    }
    // stage V transposed: reg -> LDS [d][key], swizzled
#pragma unroll
    for (int i = 0; i < 2; ++i) {
      int idx = t + 256 * i;
      int key = idx >> 3, dc = idx & 7;
      bf16x8 v = *reinterpret_cast<const bf16x8*>(
          qkv + (size_t)(b * SEQ + s0 + key) * N_QKV + h * 192 + 128 + dc * 8);
#pragma unroll
      for (int e = 0; e < 8; ++e) {
        int d = dc * 8 + e;
        int byteoff = d * 128 + (((key >> 3) ^ (d & 7)) * 16) + (key & 7) * 2;
        *(uint16_t*)((char*)Vt + byteoff) = (uint16_t)v[e];
      }
    }
    __syncthreads();  // drains vmcnt + lgkmcnt

    // S = Q @ K^T  (16 q-rows x 64 keys per wave)
    f32x4 s[4] = {};
#pragma unroll
    for (int c = 0; c < 4; ++c) {
#pragma unroll
      for (int kk = 0; kk < 2; ++kk) {
        int row = c * 16 + l15;
        int sl = (kk * 4 + l4) ^ (row & 7);
        bf16x8 kf = *reinterpret_cast<const bf16x8*>((const char*)Kt + row * 128 + sl * 16);
        s[c] = __builtin_amdgcn_mfma_f32_16x16x32_bf16(qf[kk], kf, s[c], 0, 0, 0);
      }
    }

    // online softmax (rows (l>>4)*4+jj, reduce across the 16 lanes of l&15)
    float scale[4], tsum[4];
#pragma unroll
    for (int jj = 0; jj < 4; ++jj) {
      float v = fmaxf(fmaxf(s[0][jj], s[1][jj]), fmaxf(s[2][jj], s[3][jj]));
#pragma unroll
      for (int m = 8; m >= 1; m >>= 1) v = fmaxf(v, __shfl_xor(v, m, 64));
      float mn = fmaxf(mrow[jj], v);
      scale[jj] = __expf(mrow[jj] - mn);
      mrow[jj] = mn;
      tsum[jj] = 0.0f;
    }
#pragma unroll
    for (int c = 0; c < 4; ++c) {
#pragma unroll
      for (int jj = 0; jj < 4; ++jj) {
        float p = __expf(s[c][jj] - mrow[jj]);
        tsum[jj] += p;
        int row = l4 * 4 + jj;
        int col = c * 16 + l15;
        int byteoff = row * 128 + (((col >> 3) ^ (row & 7)) * 16) + (col & 7) * 2;
        *(uint16_t*)((char*)Pl[w] + byteoff) = f2bf(p);
      }
    }
#pragma unroll
    for (int jj = 0; jj < 4; ++jj) {
      float v = tsum[jj];
#pragma unroll
      for (int m = 8; m >= 1; m >>= 1) v += __shfl_xor(v, m, 64);
      lrow[jj] = lrow[jj] * scale[jj] + v;
    }
#pragma unroll
    for (int f = 0; f < 4; ++f)
#pragma unroll
      for (int jj = 0; jj < 4; ++jj) o[f][jj] *= scale[jj];

    // O += P @ V
#pragma unroll
    for (int kk = 0; kk < 2; ++kk) {
      int sp = (kk * 4 + l4) ^ (l15 & 7);
      bf16x8 pa = *reinterpret_cast<const bf16x8*>((const char*)Pl[w] + l15 * 128 + sp * 16);
#pragma unroll
      for (int f = 0; f < 4; ++f) {
        int d = f * 16 + l15;
        int sv = (kk * 4 + l4) ^ (d & 7);
        bf16x8 vf = *reinterpret_cast<const bf16x8*>((const char*)Vt + d * 128 + sv * 16);
        o[f] = __builtin_amdgcn_mfma_f32_16x16x32_bf16(pa, vf, o[f], 0, 0, 0);
      }
    }
  }

  // normalize + write out[b, q, h*64+d] fp32
#pragma unroll
  for (int f = 0; f < 4; ++f) {
    int d = f * 16 + l15;
#pragma unroll
    for (int jj = 0; jj < 4; ++jj) {
      int q = qw + l4 * 4 + jj;
      out[(size_t)(b * SEQ + q) * HD + h * 64 + d] = o[f][jj] / lrow[jj];
    }
  }
}

extern "C" void kernel_launch(void* const* d_in, const int* in_sizes, int n_in,
                              void* d_out, int out_size, void* d_ws, size_t ws_size,
                              hipStream_t stream) {
  const float* x = (const float*)d_in[0];
  const float* Wq = (const float*)d_in[1];
  float* out = (float*)d_out;

  uint16_t* xb = (uint16_t*)d_ws;                       // 4096*512 bf16
  uint16_t* Wb = xb + (size_t)M_TOTAL * K_DIM;          // 1536*512 bf16
  uint16_t* qkv = Wb + (size_t)N_QKV * K_DIM;           // 4096*1536 bf16

  convert_f32_to_bf16<<<(M_TOTAL * K_DIM / 4 + 255) / 256, 256, 0, stream>>>(
      x, xb, M_TOTAL * K_DIM / 4);
  convert_f32_to_bf16<<<(N_QKV * K_DIM / 4 + 255) / 256, 256, 0, stream>>>(
      Wq, Wb, N_QKV * K_DIM / 4);

  dim3 g1(N_QKV / BN, M_TOTAL / BM);
  qkv_gemm<<<g1, 256, 0, stream>>>(xb, Wb, qkv);

  dim3 g2(SEQ / 64, BATCH * NH);
  attn<<<g2, 256, 0, stream>>>(qkv, out);
}

// Round 2
// 151.977 us; speedup vs baseline: 1.0643x; 1.0643x over previous
//
#include <hip/hip_runtime.h>
#include <stdint.h>

#define HD 512
#define NH 8
#define DH 64
#define SEQ 2048
#define BATCH 2
#define M_TOTAL (BATCH*SEQ)   // 4096
#define N_QKV (3*HD)          // 1536
#define K_DIM HD              // 512

typedef short bf16x8 __attribute__((ext_vector_type(8)));
typedef float f32x4 __attribute__((ext_vector_type(4)));

__device__ __forceinline__ uint16_t f2bf(float f) {
  union { float f; uint32_t u; } v; v.f = f;
  uint32_t u = v.u;
  return (uint16_t)((u + 0x7FFFu + ((u >> 16) & 1u)) >> 16);
}

__device__ __forceinline__ void gload_lds16(const void* g, void* l) {
  __builtin_amdgcn_global_load_lds(
      (const __attribute__((address_space(1))) void*)g,
      (__attribute__((address_space(3))) void*)l,
      16, 0, 0);
}

__global__ void convert_f32_to_bf16(const float* __restrict__ in,
                                    uint16_t* __restrict__ out, int n4) {
  int i = blockIdx.x * blockDim.x + threadIdx.x;
  if (i < n4) {
    float4 v = reinterpret_cast<const float4*>(in)[i];
    ushort4 o;
    o.x = f2bf(v.x); o.y = f2bf(v.y); o.z = f2bf(v.z); o.w = f2bf(v.w);
    reinterpret_cast<ushort4*>(out)[i] = o;
  }
}

// ---------------- QKV GEMM: C[4096,1536] = X[4096,512] @ W^T (W is [1536,512]) ----
// Q columns scaled by temperature and written to qkv; K written to qkv;
// V columns written TRANSPOSED to Vt[bh][d][s].
#define BM 128
#define BN 128
#define BK 64
#define NKT (K_DIM / BK)      // 8

__global__ __launch_bounds__(256)
void qkv_gemm(const uint16_t* __restrict__ A,   // x bf16 [4096][512]
              const uint16_t* __restrict__ Bw,  // W bf16 [1536][512]
              uint16_t* __restrict__ C,         // qkv bf16 [4096][1536] (q,k parts)
              uint16_t* __restrict__ Vt) {      // [16][64][2048] bf16
  __shared__ __align__(16) uint16_t As[2][BM * BK];
  __shared__ __align__(16) uint16_t Bs[2][BM * BK];

  const int t = threadIdx.x;
  const int lane = t & 63;
  const int w = t >> 6;
  const int wr = w >> 1, wc = w & 1;
  const int l15 = lane & 15, l4 = lane >> 4;
  const int m0 = blockIdx.y * BM;
  const int n0 = blockIdx.x * BN;

  f32x4 acc[4][4] = {};

  // stage tile kt into buf
  auto stage = [&](int kt, int buf) {
#pragma unroll
    for (int i = 0; i < 4; ++i) {
      int idx = t + 256 * i;              // 0..1023 : row(128) x slot(8)
      int row = idx >> 3, slot = idx & 7;
      int src = slot ^ (row & 7);         // inverse-swizzle the SOURCE
      gload_lds16(A + (size_t)(m0 + row) * K_DIM + kt * BK + src * 8,
                  (char*)As[buf] + idx * 16);
      gload_lds16(Bw + (size_t)(n0 + row) * K_DIM + kt * BK + src * 8,
                  (char*)Bs[buf] + idx * 16);
    }
  };

  stage(0, 0);
  for (int kt = 0; kt < NKT; ++kt) {
    __syncthreads();                       // drains my gloads (vmcnt 0) + barrier
    if (kt + 1 < NKT) stage(kt + 1, (kt + 1) & 1);
    const char* Ab = (const char*)As[kt & 1];
    const char* Bb = (const char*)Bs[kt & 1];
#pragma unroll
    for (int kk = 0; kk < 2; ++kk) {      // two K=32 sub-steps
      bf16x8 af[4], bfr[4];
#pragma unroll
      for (int i = 0; i < 4; ++i) {
        int rowa = wr * 64 + i * 16 + l15;
        int sa = (kk * 4 + l4) ^ (rowa & 7);
        af[i] = *reinterpret_cast<const bf16x8*>(Ab + rowa * 128 + sa * 16);
        int rowb = wc * 64 + i * 16 + l15;
        int sb = (kk * 4 + l4) ^ (rowb & 7);
        bfr[i] = *reinterpret_cast<const bf16x8*>(Bb + rowb * 128 + sb * 16);
      }
#pragma unroll
      for (int i = 0; i < 4; ++i)
#pragma unroll
        for (int j = 0; j < 4; ++j)
          acc[i][j] = __builtin_amdgcn_mfma_f32_16x16x32_bf16(af[i], bfr[j], acc[i][j], 0, 0, 0);
    }
  }

  // epilogue: q scaled by 0.125 -> qkv; k -> qkv; v -> Vt transposed
#pragma unroll
  for (int i = 0; i < 4; ++i) {
    int row = m0 + wr * 64 + i * 16 + l4 * 4;
#pragma unroll
    for (int j = 0; j < 4; ++j) {
      int colb = n0 + wc * 64 + j * 16;      // multiple of 16 -> class uniform
      int col = colb + l15;
      int cls = (colb % 192) >> 6;           // 0=q 1=k 2=v
      if (cls == 2) {
        int h = col / 192;
        int d = col - h * 192 - 128;
        int b = row >> 11;
        int s = row & (SEQ - 1);
        ushort4 o;
        o.x = f2bf(acc[i][j][0]); o.y = f2bf(acc[i][j][1]);
        o.z = f2bf(acc[i][j][2]); o.w = f2bf(acc[i][j][3]);
        *reinterpret_cast<ushort4*>(Vt + ((size_t)(b * NH + h) * DH + d) * SEQ + s) = o;
      } else {
        float sc = (cls == 0) ? 0.125f : 1.0f;
#pragma unroll
        for (int jj = 0; jj < 4; ++jj)
          C[(size_t)(row + jj) * N_QKV + col] = f2bf(acc[i][j][jj] * sc);
      }
    }
  }
}

// ---------------- Flash attention: per (b,h), Q-block 64 rows, KV tiles of 64 ----
#define NT (SEQ / 64)          // 32 kv tiles

__global__ __launch_bounds__(256)
void attn(const uint16_t* __restrict__ qkv, const uint16_t* __restrict__ VtG,
          float* __restrict__ out) {
  __shared__ __align__(16) uint16_t Kt[2][64 * 64];   // [key][d] swizzled slots
  __shared__ __align__(16) uint16_t Vt[2][64 * 64];   // [d][key] swizzled slots
  __shared__ __align__(16) uint16_t Pl[4][16 * 64];   // per-wave [q][key] swizzled

  const int t = threadIdx.x;
  const int lane = t & 63;
  const int w = t >> 6;
  const int l15 = lane & 15, l4 = lane >> 4;
  const int bh = blockIdx.y;
  const int b = bh >> 3, h = bh & 7;
  const int q0 = blockIdx.x * 64;
  const int qw = q0 + w * 16;

  // Q fragments (q pre-scaled by temperature in GEMM epilogue)
  bf16x8 qf[2];
  {
    const uint16_t* qp = qkv + (size_t)(b * SEQ + qw + l15) * N_QKV + h * 192;
#pragma unroll
    for (int kk = 0; kk < 2; ++kk)
      qf[kk] = *reinterpret_cast<const bf16x8*>(qp + kk * 32 + l4 * 8);
  }

  const uint16_t* kgbase = qkv + (size_t)b * SEQ * N_QKV + h * 192 + 64;
  const uint16_t* vgbase = VtG + (size_t)bh * DH * SEQ;

  auto stage = [&](int ti, int buf) {
    int s0 = ti * 64;
#pragma unroll
    for (int i = 0; i < 2; ++i) {
      int idx = t + 256 * i;
      int row = idx >> 3, slot = idx & 7;
      int src = slot ^ (row & 7);
      gload_lds16(kgbase + (size_t)(s0 + row) * N_QKV + src * 8,
                  (char*)Kt[buf] + idx * 16);
      gload_lds16(vgbase + (size_t)row * SEQ + s0 + src * 8,
                  (char*)Vt[buf] + idx * 16);
    }
  };

  f32x4 o[4] = {};
  float mrow[4], lrow[4];
#pragma unroll
  for (int jj = 0; jj < 4; ++jj) { mrow[jj] = -1e30f; lrow[jj] = 0.0f; }

  stage(0, 0);
  for (int ti = 0; ti < NT; ++ti) {
    __syncthreads();                       // vmcnt(0) + barrier: tile ti ready
    if (ti + 1 < NT) stage(ti + 1, (ti + 1) & 1);
    const char* Kb = (const char*)Kt[ti & 1];
    const char* Vb = (const char*)Vt[ti & 1];

    // S = Q @ K^T  (16 q-rows x 64 keys per wave)
    f32x4 s[4] = {};
#pragma unroll
    for (int c = 0; c < 4; ++c) {
#pragma unroll
      for (int kk = 0; kk < 2; ++kk) {
        int row = c * 16 + l15;
        int sl = (kk * 4 + l4) ^ (row & 7);
        bf16x8 kf = *reinterpret_cast<const bf16x8*>(Kb + row * 128 + sl * 16);
        s[c] = __builtin_amdgcn_mfma_f32_16x16x32_bf16(qf[kk], kf, s[c], 0, 0, 0);
      }
    }

    // online softmax (rows l4*4+jj, reduce across 16 lanes of l15)
    float scale[4], tsum[4];
#pragma unroll
    for (int jj = 0; jj < 4; ++jj) {
      float v = fmaxf(fmaxf(s[0][jj], s[1][jj]), fmaxf(s[2][jj], s[3][jj]));
#pragma unroll
      for (int m = 8; m >= 1; m >>= 1) v = fmaxf(v, __shfl_xor(v, m, 64));
      float mn = fmaxf(mrow[jj], v);
      scale[jj] = __expf(mrow[jj] - mn);
      mrow[jj] = mn;
      tsum[jj] = 0.0f;
    }
#pragma unroll
    for (int c = 0; c < 4; ++c) {
#pragma unroll
      for (int jj = 0; jj < 4; ++jj) {
        float p = __expf(s[c][jj] - mrow[jj]);
        tsum[jj] += p;
        int row = l4 * 4 + jj;
        int col = c * 16 + l15;
        int byteoff = row * 128 + (((col >> 3) ^ (row & 7)) * 16) + (col & 7) * 2;
        *(uint16_t*)((char*)Pl[w] + byteoff) = f2bf(p);
      }
    }
#pragma unroll
    for (int jj = 0; jj < 4; ++jj) {
      float v = tsum[jj];
#pragma unroll
      for (int m = 8; m >= 1; m >>= 1) v += __shfl_xor(v, m, 64);
      lrow[jj] = lrow[jj] * scale[jj] + v;
    }
#pragma unroll
    for (int f = 0; f < 4; ++f)
#pragma unroll
      for (int jj = 0; jj < 4; ++jj) o[f][jj] *= scale[jj];

    // O += P @ V
#pragma unroll
    for (int kk = 0; kk < 2; ++kk) {
      int sp = (kk * 4 + l4) ^ (l15 & 7);
      bf16x8 pa = *reinterpret_cast<const bf16x8*>((const char*)Pl[w] + l15 * 128 + sp * 16);
#pragma unroll
      for (int f = 0; f < 4; ++f) {
        int d = f * 16 + l15;
        int sv = (kk * 4 + l4) ^ (d & 7);
        bf16x8 vf = *reinterpret_cast<const bf16x8*>(Vb + d * 128 + sv * 16);
        o[f] = __builtin_amdgcn_mfma_f32_16x16x32_bf16(pa, vf, o[f], 0, 0, 0);
      }
    }
  }

  // normalize + write out[b, q, h*64+d] fp32
#pragma unroll
  for (int f = 0; f < 4; ++f) {
    int d = f * 16 + l15;
#pragma unroll
    for (int jj = 0; jj < 4; ++jj) {
      int q = qw + l4 * 4 + jj;
      out[(size_t)(b * SEQ + q) * HD + h * 64 + d] = o[f][jj] / lrow[jj];
    }
  }
}

extern "C" void kernel_launch(void* const* d_in, const int* in_sizes, int n_in,
                              void* d_out, int out_size, void* d_ws, size_t ws_size,
                              hipStream_t stream) {
  const float* x = (const float*)d_in[0];
  const float* Wq = (const float*)d_in[1];
  float* out = (float*)d_out;

  uint16_t* xb = (uint16_t*)d_ws;                       // 4096*512 bf16
  uint16_t* Wb = xb + (size_t)M_TOTAL * K_DIM;          // 1536*512 bf16
  uint16_t* qkv = Wb + (size_t)N_QKV * K_DIM;           // 4096*1536 bf16
  uint16_t* vtg = qkv + (size_t)M_TOTAL * N_QKV;        // 16*64*2048 bf16

  convert_f32_to_bf16<<<(M_TOTAL * K_DIM / 4 + 255) / 256, 256, 0, stream>>>(
      x, xb, M_TOTAL * K_DIM / 4);
  convert_f32_to_bf16<<<(N_QKV * K_DIM / 4 + 255) / 256, 256, 0, stream>>>(
      Wq, Wb, N_QKV * K_DIM / 4);

  dim3 g1(N_QKV / BN, M_TOTAL / BM);
  qkv_gemm<<<g1, 256, 0, stream>>>(xb, Wb, qkv, vtg);

  dim3 g2(SEQ / 64, BATCH * NH);
  attn<<<g2, 256, 0, stream>>>(qkv, vtg, out);
}

// Round 3
// 125.334 us; speedup vs baseline: 1.2905x; 1.2126x over previous
//
#include <hip/hip_runtime.h>
#include <stdint.h>

#define HD 512
#define NH 8
#define DH 64
#define SEQ 2048
#define BATCH 2
#define M_TOTAL (BATCH*SEQ)   // 4096
#define N_QKV (3*HD)          // 1536
#define K_DIM HD              // 512

typedef short bf16x8 __attribute__((ext_vector_type(8)));
typedef float f32x4 __attribute__((ext_vector_type(4)));
typedef uint32_t u32x2 __attribute__((ext_vector_type(2)));

// q-scale: temperature 1/8 folded with log2(e) so v_exp_f32 (2^x) gives e^(s/8)
#define QSCALE 0.18033688011112042f

__device__ __forceinline__ uint16_t f2bf(float f) {
  union { float f; uint32_t u; } v; v.f = f;
  uint32_t u = v.u;
  return (uint16_t)((u + 0x7FFFu + ((u >> 16) & 1u)) >> 16);
}

__device__ __forceinline__ void gload_lds16(const void* g, void* l) {
  __builtin_amdgcn_global_load_lds(
      (const __attribute__((address_space(1))) void*)g,
      (__attribute__((address_space(3))) void*)l,
      16, 0, 0);
}

__global__ void convert_f32_to_bf16(const float* __restrict__ in,
                                    uint16_t* __restrict__ out, int n4) {
  int i = blockIdx.x * blockDim.x + threadIdx.x;
  if (i < n4) {
    float4 v = reinterpret_cast<const float4*>(in)[i];
    ushort4 o;
    o.x = f2bf(v.x); o.y = f2bf(v.y); o.z = f2bf(v.z); o.w = f2bf(v.w);
    reinterpret_cast<ushort4*>(out)[i] = o;
  }
}

// ---------------- QKV GEMM: C[4096,1536] = X[4096,512] @ W^T (W is [1536,512]) ----
#define BM 128
#define BN 128
#define BK 64
#define NKT (K_DIM / BK)      // 8

__global__ __launch_bounds__(256)
void qkv_gemm(const uint16_t* __restrict__ A,   // x bf16 [4096][512]
              const uint16_t* __restrict__ Bw,  // W bf16 [1536][512]
              uint16_t* __restrict__ C,         // qkv bf16 [4096][1536] (q,k parts)
              uint16_t* __restrict__ Vt) {      // [16][64][2048] bf16
  __shared__ __align__(16) uint16_t As[2][BM * BK];
  __shared__ __align__(16) uint16_t Bs[2][BM * BK];

  const int t = threadIdx.x;
  const int lane = t & 63;
  const int w = t >> 6;
  const int wr = w >> 1, wc = w & 1;
  const int l15 = lane & 15, l4 = lane >> 4;
  const int m0 = blockIdx.y * BM;
  const int n0 = blockIdx.x * BN;

  f32x4 acc[4][4] = {};

  auto stage = [&](int kt, int buf) {
#pragma unroll
    for (int i = 0; i < 4; ++i) {
      int idx = t + 256 * i;              // 0..1023 : row(128) x slot(8)
      int row = idx >> 3, slot = idx & 7;
      int src = slot ^ (row & 7);         // inverse-swizzle the SOURCE
      gload_lds16(A + (size_t)(m0 + row) * K_DIM + kt * BK + src * 8,
                  (char*)As[buf] + idx * 16);
      gload_lds16(Bw + (size_t)(n0 + row) * K_DIM + kt * BK + src * 8,
                  (char*)Bs[buf] + idx * 16);
    }
  };

  stage(0, 0);
  for (int kt = 0; kt < NKT; ++kt) {
    __syncthreads();                       // drains my gloads (vmcnt 0) + barrier
    if (kt + 1 < NKT) stage(kt + 1, (kt + 1) & 1);
    const char* Ab = (const char*)As[kt & 1];
    const char* Bb = (const char*)Bs[kt & 1];
#pragma unroll
    for (int kk = 0; kk < 2; ++kk) {      // two K=32 sub-steps
      bf16x8 af[4], bfr[4];
#pragma unroll
      for (int i = 0; i < 4; ++i) {
        int rowa = wr * 64 + i * 16 + l15;
        int sa = (kk * 4 + l4) ^ (rowa & 7);
        af[i] = *reinterpret_cast<const bf16x8*>(Ab + rowa * 128 + sa * 16);
        int rowb = wc * 64 + i * 16 + l15;
        int sb = (kk * 4 + l4) ^ (rowb & 7);
        bfr[i] = *reinterpret_cast<const bf16x8*>(Bb + rowb * 128 + sb * 16);
      }
      __builtin_amdgcn_s_setprio(1);
#pragma unroll
      for (int i = 0; i < 4; ++i)
#pragma unroll
        for (int j = 0; j < 4; ++j)
          acc[i][j] = __builtin_amdgcn_mfma_f32_16x16x32_bf16(af[i], bfr[j], acc[i][j], 0, 0, 0);
      __builtin_amdgcn_s_setprio(0);
    }
  }

  // epilogue: q scaled by QSCALE -> qkv; k -> qkv; v -> Vt transposed
#pragma unroll
  for (int i = 0; i < 4; ++i) {
    int row = m0 + wr * 64 + i * 16 + l4 * 4;
#pragma unroll
    for (int j = 0; j < 4; ++j) {
      int colb = n0 + wc * 64 + j * 16;      // multiple of 16 -> class uniform
      int col = colb + l15;
      int cls = (colb % 192) >> 6;           // 0=q 1=k 2=v
      if (cls == 2) {
        int h = col / 192;
        int d = col - h * 192 - 128;
        int b = row >> 11;
        int s = row & (SEQ - 1);
        ushort4 o;
        o.x = f2bf(acc[i][j][0]); o.y = f2bf(acc[i][j][1]);
        o.z = f2bf(acc[i][j][2]); o.w = f2bf(acc[i][j][3]);
        *reinterpret_cast<ushort4*>(Vt + ((size_t)(b * NH + h) * DH + d) * SEQ + s) = o;
      } else {
        float sc = (cls == 0) ? QSCALE : 1.0f;
#pragma unroll
        for (int jj = 0; jj < 4; ++jj)
          C[(size_t)(row + jj) * N_QKV + col] = f2bf(acc[i][j][jj] * sc);
      }
    }
  }
}

// ---------------- Flash attention: per (b,h), Q-block 64 rows, KV tiles of 64 ----
#define NT (SEQ / 64)          // 32 kv tiles

__global__ __launch_bounds__(256)
void attn(const uint16_t* __restrict__ qkv, const uint16_t* __restrict__ VtG,
          float* __restrict__ out) {
  __shared__ __align__(16) uint16_t Kt[2][64 * 64];   // [key][d] swizzled slots
  __shared__ __align__(16) uint16_t Vt[2][64 * 64];   // [d][key] swizzled slots
  __shared__ __align__(16) uint16_t Pl[4][16 * 64];   // per-wave [q][key] swizzled

  const int t = threadIdx.x;
  const int lane = t & 63;
  const int w = t >> 6;
  const int l15 = lane & 15, l4 = lane >> 4;
  const int bh = blockIdx.x;               // head-major: XCD = bh%8 owns 2 heads
  const int b = bh >> 3, h = bh & 7;
  const int q0 = blockIdx.y * 64;
  const int qw = q0 + w * 16;

  // Q fragments (pre-scaled by QSCALE in GEMM epilogue)
  bf16x8 qf[2];
  {
    const uint16_t* qp = qkv + (size_t)(b * SEQ + qw + l15) * N_QKV + h * 192;
#pragma unroll
    for (int kk = 0; kk < 2; ++kk)
      qf[kk] = *reinterpret_cast<const bf16x8*>(qp + kk * 32 + l4 * 8);
  }

  const uint16_t* kgbase = qkv + (size_t)b * SEQ * N_QKV + h * 192 + 64;
  const uint16_t* vgbase = VtG + (size_t)bh * DH * SEQ;

  auto stage = [&](int ti, int buf) {
    int s0 = ti * 64;
#pragma unroll
    for (int i = 0; i < 2; ++i) {
      int idx = t + 256 * i;
      int row = idx >> 3, slot = idx & 7;
      int src = slot ^ (row & 7);
      gload_lds16(kgbase + (size_t)(s0 + row) * N_QKV + src * 8,
                  (char*)Kt[buf] + idx * 16);
      gload_lds16(vgbase + (size_t)row * SEQ + s0 + src * 8,
                  (char*)Vt[buf] + idx * 16);
    }
  };

  f32x4 o[4] = {};
  float mrow = -1e30f, lrow = 0.0f;        // per-lane state for q = l15

  stage(0, 0);
  for (int ti = 0; ti < NT; ++ti) {
    __syncthreads();                       // vmcnt(0) + barrier: tile ti ready
    if (ti + 1 < NT) stage(ti + 1, (ti + 1) & 1);
    const char* Kb = (const char*)Kt[ti & 1];
    const char* Vb = (const char*)Vt[ti & 1];

    // S^T = K @ Q^T : swapped operands, same fragments.
    // s[c]: C[row = key_in_block = l4*4+jj][col = q = l15], key = c*16 + l4*4 + jj
    f32x4 s[4] = {};
#pragma unroll
    for (int c = 0; c < 4; ++c) {
#pragma unroll
      for (int kk = 0; kk < 2; ++kk) {
        int row = c * 16 + l15;
        int sl = (kk * 4 + l4) ^ (row & 7);
        bf16x8 kf = *reinterpret_cast<const bf16x8*>(Kb + row * 128 + sl * 16);
        __builtin_amdgcn_s_setprio(1);
        s[c] = __builtin_amdgcn_mfma_f32_16x16x32_bf16(kf, qf[kk], s[c], 0, 0, 0);
        __builtin_amdgcn_s_setprio(0);
      }
    }

    // lane-local softmax for q = l15 over 16 in-lane keys + 2 cross-lane steps
    float vmax = s[0][0];
#pragma unroll
    for (int c = 0; c < 4; ++c)
#pragma unroll
      for (int jj = 0; jj < 4; ++jj) vmax = fmaxf(vmax, s[c][jj]);
    vmax = fmaxf(vmax, __shfl_xor(vmax, 16, 64));
    vmax = fmaxf(vmax, __shfl_xor(vmax, 32, 64));

    if (!__all(vmax - mrow <= 11.0f)) {    // defer-max (log2 domain, e^~7.6)
      float mn = fmaxf(mrow, vmax);
      float sc;
      float darg = mrow - mn;
      asm("v_exp_f32 %0, %1" : "=v"(sc) : "v"(darg));
      mrow = mn;
      float sr[4];
#pragma unroll
      for (int jj = 0; jj < 4; ++jj) sr[jj] = __shfl(sc, l4 * 4 + jj, 64);
#pragma unroll
      for (int f = 0; f < 4; ++f)
#pragma unroll
        for (int jj = 0; jj < 4; ++jj) o[f][jj] *= sr[jj];
      lrow *= sc;
    }

    float p[16];
#pragma unroll
    for (int c = 0; c < 4; ++c)
#pragma unroll
      for (int jj = 0; jj < 4; ++jj) {
        float arg = s[c][jj] - mrow;
        float e;
        asm("v_exp_f32 %0, %1" : "=v"(e) : "v"(arg));   // 2^x (log2-domain scores)
        p[c * 4 + jj] = e;
      }
    // pairwise sum tree (15 adds) + 2 cross-lane steps
    float a0 = (p[0] + p[1]) + (p[2] + p[3]);
    float a1 = (p[4] + p[5]) + (p[6] + p[7]);
    float a2 = (p[8] + p[9]) + (p[10] + p[11]);
    float a3 = (p[12] + p[13]) + (p[14] + p[15]);
    float tsum = (a0 + a1) + (a2 + a3);
    tsum += __shfl_xor(tsum, 16, 64);
    tsum += __shfl_xor(tsum, 32, 64);
    lrow += tsum;

    // pack P (4 consecutive keys per c) and store: one b64 per c
#pragma unroll
    for (int c = 0; c < 4; ++c) {
      uint32_t lo, hi;
      asm("v_cvt_pk_bf16_f32 %0, %1, %2" : "=v"(lo) : "v"(p[c * 4 + 0]), "v"(p[c * 4 + 1]));
      asm("v_cvt_pk_bf16_f32 %0, %1, %2" : "=v"(hi) : "v"(p[c * 4 + 2]), "v"(p[c * 4 + 3]));
      int slot = 2 * c + (l4 >> 1);                      // col>>3, col = 16c+4*l4
      int byteoff = l15 * 128 + ((slot ^ (l15 & 7)) * 16) + (l4 & 1) * 8;
      u32x2 pk; pk.x = lo; pk.y = hi;
      *reinterpret_cast<u32x2*>((char*)Pl[w] + byteoff) = pk;
    }

    // O += P @ V  (pa: A-frag row=q=l15; vf: B-frag col=d) — unchanged layout
#pragma unroll
    for (int kk = 0; kk < 2; ++kk) {
      int sp = (kk * 4 + l4) ^ (l15 & 7);
      bf16x8 pa = *reinterpret_cast<const bf16x8*>((const char*)Pl[w] + l15 * 128 + sp * 16);
      __builtin_amdgcn_s_setprio(1);
#pragma unroll
      for (int f = 0; f < 4; ++f) {
        int d = f * 16 + l15;
        int sv = (kk * 4 + l4) ^ (d & 7);
        bf16x8 vf = *reinterpret_cast<const bf16x8*>(Vb + d * 128 + sv * 16);
        o[f] = __builtin_amdgcn_mfma_f32_16x16x32_bf16(pa, vf, o[f], 0, 0, 0);
      }
      __builtin_amdgcn_s_setprio(0);
    }
  }

  // normalize + write out[b, q, h*64+d] fp32
  float lr[4];
#pragma unroll
  for (int jj = 0; jj < 4; ++jj) lr[jj] = __shfl(lrow, l4 * 4 + jj, 64);
#pragma unroll
  for (int f = 0; f < 4; ++f) {
    int d = f * 16 + l15;
#pragma unroll
    for (int jj = 0; jj < 4; ++jj) {
      int q = qw + l4 * 4 + jj;
      out[(size_t)(b * SEQ + q) * HD + h * 64 + d] = o[f][jj] / lr[jj];
    }
  }
}

extern "C" void kernel_launch(void* const* d_in, const int* in_sizes, int n_in,
                              void* d_out, int out_size, void* d_ws, size_t ws_size,
                              hipStream_t stream) {
  const float* x = (const float*)d_in[0];
  const float* Wq = (const float*)d_in[1];
  float* out = (float*)d_out;

  uint16_t* xb = (uint16_t*)d_ws;                       // 4096*512 bf16
  uint16_t* Wb = xb + (size_t)M_TOTAL * K_DIM;          // 1536*512 bf16
  uint16_t* qkv = Wb + (size_t)N_QKV * K_DIM;           // 4096*1536 bf16
  uint16_t* vtg = qkv + (size_t)M_TOTAL * N_QKV;        // 16*64*2048 bf16

  convert_f32_to_bf16<<<(M_TOTAL * K_DIM / 4 + 255) / 256, 256, 0, stream>>>(
      x, xb, M_TOTAL * K_DIM / 4);
  convert_f32_to_bf16<<<(N_QKV * K_DIM / 4 + 255) / 256, 256, 0, stream>>>(
      Wq, Wb, N_QKV * K_DIM / 4);

  dim3 g1(N_QKV / BN, M_TOTAL / BM);
  qkv_gemm<<<g1, 256, 0, stream>>>(xb, Wb, qkv, vtg);

  dim3 g2(BATCH * NH, SEQ / 64);
  attn<<<g2, 256, 0, stream>>>(qkv, vtg, out);
}

// Round 4
// 114.604 us; speedup vs baseline: 1.4113x; 1.0936x over previous
//
#include <hip/hip_runtime.h>
#include <stdint.h>

#define HD 512
#define NH 8
#define DH 64
#define SEQ 2048
#define BATCH 2
#define M_TOTAL (BATCH*SEQ)   // 4096
#define N_QKV (3*HD)          // 1536
#define K_DIM HD              // 512

typedef short bf16x8 __attribute__((ext_vector_type(8)));
typedef float f32x4 __attribute__((ext_vector_type(4)));
typedef uint32_t u32x2 __attribute__((ext_vector_type(2)));
typedef uint32_t u32x4 __attribute__((ext_vector_type(4)));

// q-scale: temperature 1/8 folded with log2(e) so v_exp_f32 (2^x) gives e^(s/8)
#define QSCALE 0.18033688011112042f

__device__ __forceinline__ uint16_t f2bf(float f) {
  union { float f; uint32_t u; } v; v.f = f;
  uint32_t u = v.u;
  return (uint16_t)((u + 0x7FFFu + ((u >> 16) & 1u)) >> 16);
}

__device__ __forceinline__ void gload_lds16(const void* g, void* l) {
  __builtin_amdgcn_global_load_lds(
      (const __attribute__((address_space(1))) void*)g,
      (__attribute__((address_space(3))) void*)l,
      16, 0, 0);
}

__global__ void convert_f32_to_bf16(const float* __restrict__ in,
                                    uint16_t* __restrict__ out, int n4) {
  int i = blockIdx.x * blockDim.x + threadIdx.x;
  if (i < n4) {
    float4 v = reinterpret_cast<const float4*>(in)[i];
    ushort4 o;
    o.x = f2bf(v.x); o.y = f2bf(v.y); o.z = f2bf(v.z); o.w = f2bf(v.w);
    reinterpret_cast<ushort4*>(out)[i] = o;
  }
}

// ---------------- QKV GEMM: C[4096,1536] = X[4096,512] @ W^T (W is [1536,512]) ----
#define BM 128
#define BN 128
#define BK 64
#define NKT (K_DIM / BK)      // 8

__global__ __launch_bounds__(256)
void qkv_gemm(const uint16_t* __restrict__ A,   // x bf16 [4096][512]
              const uint16_t* __restrict__ Bw,  // W bf16 [1536][512]
              uint16_t* __restrict__ C,         // qkv bf16 [4096][1536] (q,k parts)
              uint16_t* __restrict__ Vt) {      // [16][64][2048] bf16
  __shared__ __align__(16) uint16_t As[2][BM * BK];   // 32 KB (reused for V transpose)
  __shared__ __align__(16) uint16_t Bs[2][BM * BK];

  const int t = threadIdx.x;
  const int lane = t & 63;
  const int w = t >> 6;
  const int wr = w >> 1, wc = w & 1;
  const int l15 = lane & 15, l4 = lane >> 4;

  // XCD-aware bijective swizzle (384 blocks, 384%8==0)
  const int nbx = gridDim.x;                       // 12
  const int nwg = nbx * gridDim.y;                 // 384
  const int cpx = nwg >> 3;                        // 48
  int id = blockIdx.y * nbx + blockIdx.x;
  int wid = (id & 7) * cpx + (id >> 3);
  const int m0 = (wid / nbx) * BM;
  const int n0 = (wid % nbx) * BN;

  f32x4 acc[4][4] = {};

  auto stage = [&](int kt, int buf) {
#pragma unroll
    for (int i = 0; i < 4; ++i) {
      int idx = t + 256 * i;              // 0..1023 : row(128) x slot(8)
      int row = idx >> 3, slot = idx & 7;
      int src = slot ^ (row & 7);         // inverse-swizzle the SOURCE
      gload_lds16(A + (size_t)(m0 + row) * K_DIM + kt * BK + src * 8,
                  (char*)As[buf] + idx * 16);
      gload_lds16(Bw + (size_t)(n0 + row) * K_DIM + kt * BK + src * 8,
                  (char*)Bs[buf] + idx * 16);
    }
  };

  stage(0, 0);
  for (int kt = 0; kt < NKT; ++kt) {
    __syncthreads();                       // drains my gloads (vmcnt 0) + barrier
    if (kt + 1 < NKT) stage(kt + 1, (kt + 1) & 1);
    const char* Ab = (const char*)As[kt & 1];
    const char* Bb = (const char*)Bs[kt & 1];
#pragma unroll
    for (int kk = 0; kk < 2; ++kk) {      // two K=32 sub-steps
      bf16x8 af[4], bfr[4];
#pragma unroll
      for (int i = 0; i < 4; ++i) {
        int rowa = wr * 64 + i * 16 + l15;
        int sa = (kk * 4 + l4) ^ (rowa & 7);
        af[i] = *reinterpret_cast<const bf16x8*>(Ab + rowa * 128 + sa * 16);
        int rowb = wc * 64 + i * 16 + l15;
        int sb = (kk * 4 + l4) ^ (rowb & 7);
        bfr[i] = *reinterpret_cast<const bf16x8*>(Bb + rowb * 128 + sb * 16);
      }
#pragma unroll
      for (int i = 0; i < 4; ++i)
#pragma unroll
        for (int j = 0; j < 4; ++j)
          acc[i][j] = __builtin_amdgcn_mfma_f32_16x16x32_bf16(af[i], bfr[j], acc[i][j], 0, 0, 0);
    }
  }

  // ---- epilogue ----
  const int colw = n0 + wc * 64;                 // wave's 64-col half, 64-aligned
  const bool isv = ((colw % 192) == 128);        // entire half is V, or none of it
  __syncthreads();                                // done reading As/Bs: reuse as scratch

  if (isv) {
    // transpose 64s x 64d through LDS -> coalesced 128B rows of Vt[bh][d][s]
    char* tb = (char*)As + w * 8192;             // per-wave 8 KB
#pragma unroll
    for (int i = 0; i < 4; ++i)
#pragma unroll
      for (int j = 0; j < 4; ++j) {
        uint32_t lo, hi;
        asm("v_cvt_pk_bf16_f32 %0, %1, %2" : "=v"(lo) : "v"(acc[i][j][0]), "v"(acc[i][j][1]));
        asm("v_cvt_pk_bf16_f32 %0, %1, %2" : "=v"(hi) : "v"(acc[i][j][2]), "v"(acc[i][j][3]));
        int dl = j * 16 + l15;
        int byteoff = dl * 128 + (((i * 2 + (l4 >> 1)) ^ (dl & 7)) * 16) + (l4 & 1) * 8;
        u32x2 pk; pk.x = lo; pk.y = hi;
        *reinterpret_cast<u32x2*>(tb + byteoff) = pk;
      }
    int h = colw / 192;
    int b = (m0 + wr * 64) >> 11;
    int sbase = (m0 + wr * 64) & (SEQ - 1);
    uint16_t* vbase = Vt + (size_t)(b * NH + h) * DH * SEQ + sbase + (lane & 7) * 8;
#pragma unroll
    for (int p = 0; p < 8; ++p) {
      int dl = p * 8 + (lane >> 3);
      u32x4 rv = *reinterpret_cast<const u32x4*>(
          tb + dl * 128 + (((lane & 7) ^ (dl & 7)) * 16));
      *reinterpret_cast<u32x4*>(vbase + (size_t)dl * SEQ) = rv;
    }
  } else {
    // q (scaled) / k rows -> qkv
#pragma unroll
    for (int i = 0; i < 4; ++i) {
      int row = m0 + wr * 64 + i * 16 + l4 * 4;
#pragma unroll
      for (int j = 0; j < 4; ++j) {
        int colb = colw + j * 16;
        int col = colb + l15;
        float sc = (((colb % 192) >> 6) == 0) ? QSCALE : 1.0f;
#pragma unroll
        for (int jj = 0; jj < 4; ++jj)
          C[(size_t)(row + jj) * N_QKV + col] = f2bf(acc[i][j][jj] * sc);
      }
    }
  }
}

// ---------------- Flash attention, split-KV: partials (o unnorm, m, l) ----
#define NT (SEQ / 64)          // 32 kv tiles total

__global__ __launch_bounds__(256)
void attn(const uint16_t* __restrict__ qkv, const uint16_t* __restrict__ VtG,
          float* __restrict__ Po,      // [half][16][2048][64] f32 unnormalized
          float2* __restrict__ Pml) {  // [half][16][2048] (m, l)
  __shared__ __align__(16) uint16_t Kt[2][64 * 64];   // [key][d] swizzled slots
  __shared__ __align__(16) uint16_t Vt[2][64 * 64];   // [d][key] swizzled slots
  __shared__ __align__(16) uint16_t Pl[4][16 * 64];   // per-wave [q][key] swizzled

  const int t = threadIdx.x;
  const int lane = t & 63;
  const int w = t >> 6;
  const int l15 = lane & 15, l4 = lane >> 4;
  const int bh = blockIdx.x;               // head-major: XCD = bh%8 owns 2 heads
  const int b = bh >> 3, h = bh & 7;
  const int q0 = blockIdx.y * 64;
  const int qw = q0 + w * 16;
  const int half = blockIdx.z;
  const int tph = NT / gridDim.z;
  const int t0 = half * tph;

  // Q fragments (pre-scaled by QSCALE in GEMM epilogue)
  bf16x8 qf[2];
  {
    const uint16_t* qp = qkv + (size_t)(b * SEQ + qw + l15) * N_QKV + h * 192;
#pragma unroll
    for (int kk = 0; kk < 2; ++kk)
      qf[kk] = *reinterpret_cast<const bf16x8*>(qp + kk * 32 + l4 * 8);
  }

  const uint16_t* kgbase = qkv + (size_t)b * SEQ * N_QKV + h * 192 + 64;
  const uint16_t* vgbase = VtG + (size_t)bh * DH * SEQ;

  auto stage = [&](int ti, int buf) {
    int s0 = ti * 64;
#pragma unroll
    for (int i = 0; i < 2; ++i) {
      int idx = t + 256 * i;
      int row = idx >> 3, slot = idx & 7;
      int src = slot ^ (row & 7);
      gload_lds16(kgbase + (size_t)(s0 + row) * N_QKV + src * 8,
                  (char*)Kt[buf] + idx * 16);
      gload_lds16(vgbase + (size_t)row * SEQ + s0 + src * 8,
                  (char*)Vt[buf] + idx * 16);
    }
  };

  f32x4 o[4] = {};
  float mrow = -1e30f, lrow = 0.0f;        // per-lane state for q = l15

  stage(t0, 0);
  for (int rel = 0; rel < tph; ++rel) {
    int ti = t0 + rel;
    __syncthreads();                       // vmcnt(0) + barrier: tile ti ready
    if (rel + 1 < tph) stage(ti + 1, (rel + 1) & 1);
    const char* Kb = (const char*)Kt[rel & 1];
    const char* Vb = (const char*)Vt[rel & 1];

    // S^T = K @ Q^T : swapped operands.
    // s[c]: C[row = key_in_block = l4*4+jj][col = q = l15], key = c*16 + l4*4 + jj
    f32x4 s[4] = {};
    __builtin_amdgcn_s_setprio(1);
#pragma unroll
    for (int c = 0; c < 4; ++c) {
#pragma unroll
      for (int kk = 0; kk < 2; ++kk) {
        int row = c * 16 + l15;
        int sl = (kk * 4 + l4) ^ (row & 7);
        bf16x8 kf = *reinterpret_cast<const bf16x8*>(Kb + row * 128 + sl * 16);
        s[c] = __builtin_amdgcn_mfma_f32_16x16x32_bf16(kf, qf[kk], s[c], 0, 0, 0);
      }
    }
    __builtin_amdgcn_s_setprio(0);

    // lane-local softmax for q = l15 over 16 in-lane keys + 2 cross-lane steps
    float vmax = s[0][0];
#pragma unroll
    for (int c = 0; c < 4; ++c)
#pragma unroll
      for (int jj = 0; jj < 4; ++jj) vmax = fmaxf(vmax, s[c][jj]);
    vmax = fmaxf(vmax, __shfl_xor(vmax, 16, 64));
    vmax = fmaxf(vmax, __shfl_xor(vmax, 32, 64));

    if (!__all(vmax - mrow <= 11.0f)) {    // defer-max (log2 domain)
      float mn = fmaxf(mrow, vmax);
      float sc;
      float darg = mrow - mn;
      asm("v_exp_f32 %0, %1" : "=v"(sc) : "v"(darg));
      mrow = mn;
      float sr[4];
#pragma unroll
      for (int jj = 0; jj < 4; ++jj) sr[jj] = __shfl(sc, l4 * 4 + jj, 64);
#pragma unroll
      for (int f = 0; f < 4; ++f)
#pragma unroll
        for (int jj = 0; jj < 4; ++jj) o[f][jj] *= sr[jj];
      lrow *= sc;
    }

    float p[16];
#pragma unroll
    for (int c = 0; c < 4; ++c)
#pragma unroll
      for (int jj = 0; jj < 4; ++jj) {
        float arg = s[c][jj] - mrow;
        float e;
        asm("v_exp_f32 %0, %1" : "=v"(e) : "v"(arg));   // 2^x (log2-domain scores)
        p[c * 4 + jj] = e;
      }
    float a0 = (p[0] + p[1]) + (p[2] + p[3]);
    float a1 = (p[4] + p[5]) + (p[6] + p[7]);
    float a2 = (p[8] + p[9]) + (p[10] + p[11]);
    float a3 = (p[12] + p[13]) + (p[14] + p[15]);
    float tsum = (a0 + a1) + (a2 + a3);
    tsum += __shfl_xor(tsum, 16, 64);
    tsum += __shfl_xor(tsum, 32, 64);
    lrow += tsum;

    // pack P (4 consecutive keys per c) and store: one b64 per c
#pragma unroll
    for (int c = 0; c < 4; ++c) {
      uint32_t lo, hi;
      asm("v_cvt_pk_bf16_f32 %0, %1, %2" : "=v"(lo) : "v"(p[c * 4 + 0]), "v"(p[c * 4 + 1]));
      asm("v_cvt_pk_bf16_f32 %0, %1, %2" : "=v"(hi) : "v"(p[c * 4 + 2]), "v"(p[c * 4 + 3]));
      int slot = 2 * c + (l4 >> 1);                      // col>>3, col = 16c+4*l4
      int byteoff = l15 * 128 + ((slot ^ (l15 & 7)) * 16) + (l4 & 1) * 8;
      u32x2 pk; pk.x = lo; pk.y = hi;
      *reinterpret_cast<u32x2*>((char*)Pl[w] + byteoff) = pk;
    }

    // O += P @ V
    __builtin_amdgcn_s_setprio(1);
#pragma unroll
    for (int kk = 0; kk < 2; ++kk) {
      int sp = (kk * 4 + l4) ^ (l15 & 7);
      bf16x8 pa = *reinterpret_cast<const bf16x8*>((const char*)Pl[w] + l15 * 128 + sp * 16);
#pragma unroll
      for (int f = 0; f < 4; ++f) {
        int d = f * 16 + l15;
        int sv = (kk * 4 + l4) ^ (d & 7);
        bf16x8 vf = *reinterpret_cast<const bf16x8*>(Vb + d * 128 + sv * 16);
        o[f] = __builtin_amdgcn_mfma_f32_16x16x32_bf16(pa, vf, o[f], 0, 0, 0);
      }
    }
    __builtin_amdgcn_s_setprio(0);
  }

  // write partials: o unnormalized f32, (m,l) per q-row
  float* pob = Po + ((size_t)(half * 16 + bh) * SEQ) * DH;
#pragma unroll
  for (int f = 0; f < 4; ++f) {
    int d = f * 16 + l15;
#pragma unroll
    for (int jj = 0; jj < 4; ++jj) {
      int q = qw + l4 * 4 + jj;
      pob[(size_t)q * DH + d] = o[f][jj];
    }
  }
  if (lane < 16) {
    float2 ml; ml.x = mrow; ml.y = lrow;
    Pml[(size_t)(half * 16 + bh) * SEQ + qw + lane] = ml;
  }
}

// ---------------- combine partials -> out[b][q][h*64+d] ----
__global__ __launch_bounds__(256)
void attn_combine(const float* __restrict__ Po, const float2* __restrict__ Pml,
                  float* __restrict__ out, int nsplit) {
  int idx = blockIdx.x * 256 + threadIdx.x;   // 16bh * 2048q * 16 d4
  int d4 = idx & 15;
  int q = (idx >> 4) & (SEQ - 1);
  int bh = idx >> 15;
  int b = bh >> 3, h = bh & 7;

  float2 ml0 = Pml[(size_t)bh * SEQ + q];
  f32x4 o0 = *reinterpret_cast<const f32x4*>(
      Po + ((size_t)bh * SEQ + q) * DH + d4 * 4);
  f32x4 res;
  if (nsplit == 2) {
    float2 ml1 = Pml[(size_t)(16 + bh) * SEQ + q];
    f32x4 o1 = *reinterpret_cast<const f32x4*>(
        Po + ((size_t)(16 + bh) * SEQ + q) * DH + d4 * 4);
    float m = fmaxf(ml0.x, ml1.x);
    float a0 = exp2f(ml0.x - m), a1 = exp2f(ml1.x - m);
    float rden = 1.0f / (ml0.y * a0 + ml1.y * a1);
#pragma unroll
    for (int i = 0; i < 4; ++i) res[i] = (o0[i] * a0 + o1[i] * a1) * rden;
  } else {
    float rden = 1.0f / ml0.y;
#pragma unroll
    for (int i = 0; i < 4; ++i) res[i] = o0[i] * rden;
  }
  *reinterpret_cast<f32x4*>(out + ((size_t)(b * SEQ + q) * HD) + h * 64 + d4 * 4) = res;
}

extern "C" void kernel_launch(void* const* d_in, const int* in_sizes, int n_in,
                              void* d_out, int out_size, void* d_ws, size_t ws_size,
                              hipStream_t stream) {
  const float* x = (const float*)d_in[0];
  const float* Wq = (const float*)d_in[1];
  float* out = (float*)d_out;

  uint16_t* xb = (uint16_t*)d_ws;                       // 4096*512 bf16   (4 MB)
  uint16_t* Wb = xb + (size_t)M_TOTAL * K_DIM;          // 1536*512 bf16   (1.5 MB)
  uint16_t* qkv = Wb + (size_t)N_QKV * K_DIM;           // 4096*1536 bf16  (12.6 MB)
  uint16_t* vtg = qkv + (size_t)M_TOTAL * N_QKV;        // 16*64*2048 bf16 (4 MB)
  float* Po = (float*)(vtg + (size_t)16 * DH * SEQ);    // 2*16*2048*64 f32 (16.8 MB)
  float2* Pml = (float2*)(Po + (size_t)2 * 16 * SEQ * DH);  // 2*16*2048 f32x2 (0.5 MB)
  size_t need2 = (char*)(Pml + (size_t)2 * 16 * SEQ) - (char*)d_ws;
  int nsplit = (ws_size >= need2) ? 2 : 1;

  convert_f32_to_bf16<<<(M_TOTAL * K_DIM / 4 + 255) / 256, 256, 0, stream>>>(
      x, xb, M_TOTAL * K_DIM / 4);
  convert_f32_to_bf16<<<(N_QKV * K_DIM / 4 + 255) / 256, 256, 0, stream>>>(
      Wq, Wb, N_QKV * K_DIM / 4);

  dim3 g1(N_QKV / BN, M_TOTAL / BM);
  qkv_gemm<<<g1, 256, 0, stream>>>(xb, Wb, qkv, vtg);

  dim3 g2(BATCH * NH, SEQ / 64, nsplit);
  attn<<<g2, 256, 0, stream>>>(qkv, vtg, Po, Pml);

  attn_combine<<<(16 * SEQ * 16) / 256, 256, 0, stream>>>(Po, Pml, out, nsplit);
}